// Round 1
// baseline (62.451 us; speedup 1.0000x reference)
//
#include <hip/hip_runtime.h>

#define SR    9
#define SD    19
#define TS    16
#define LDSW  48               // LDS row stride: 48 ≡ 16 (mod 32) -> 2 lanes/bank, conflict-free
#define LDSH  (TS + 2*SR)      // 34
#define IMG   192

// f(t) = exp(-(t-9)^2 / 144), t = 0..18 (separable spatial gaussian factor)
__constant__ float c_FY[SD] = {
    0.5697829f, 0.6411806f, 0.7115726f, 0.7788008f, 0.8406238f,
    0.8948393f, 0.9394131f, 0.9726045f, 0.9930797f, 1.0000000f,
    0.9930797f, 0.9726045f, 0.9394131f, 0.8948393f, 0.8406238f,
    0.7788008f, 0.7115726f, 0.6411806f, 0.5697829f
};

__global__ __launch_bounds__(512) void ms_iter(const float* __restrict__ in,
                                               float* __restrict__ out) {
    __shared__ float tile[LDSH * LDSW];
    __shared__ float red_n[2][TS * TS];
    __shared__ float red_d[2][TS * TS];

    const int b   = blockIdx.z;
    const int bx0 = blockIdx.x * TS;
    const int by0 = blockIdx.y * TS;
    const float* img = in + b * IMG * IMG;

    const int tx = threadIdx.x, ty = threadIdx.y, tz = threadIdx.z;
    const int tid = tz * (TS * TS) + ty * TS + tx;

    // stage padded tile (replication pad via clamp)
    for (int i = tid; i < LDSH * LDSH; i += 512) {
        int r  = i / LDSH, c = i - r * LDSH;
        int gy = min(max(by0 + r - SR, 0), IMG - 1);
        int gx = min(max(bx0 + c - SR, 0), IMG - 1);
        tile[r * LDSW + c] = img[gy * IMG + gx];
    }
    __syncthreads();

    const float xc = tile[(ty + SR) * LDSW + (tx + SR)];

    // FX folded to immediates in the unrolled inner loop
    constexpr float FX[SD] = {
        0.5697829f, 0.6411806f, 0.7115726f, 0.7788008f, 0.8406238f,
        0.8948393f, 0.9394131f, 0.9726045f, 0.9930797f, 1.0000000f,
        0.9930797f, 0.9726045f, 0.9394131f, 0.8948393f, 0.8406238f,
        0.7788008f, 0.7115726f, 0.6411806f, 0.5697829f
    };

    const int dy_beg = tz ? 9 : 0;
    const int dy_end = tz ? SD : 9;

    float num = 0.f, den = 0.f;
    for (int dy = dy_beg; dy < dy_end; ++dy) {
        const float fy = c_FY[dy];                    // uniform -> scalar load
        const float* row = &tile[(ty + dy) * LDSW + tx];
        float rn = 0.f, rd = 0.f;
#pragma unroll
        for (int dx = 0; dx < SD; ++dx) {
            float nv = row[dx];
            float d  = xc - nv;
            // exp(-2 d^2) = exp2(d^2 * -2/ln2); range gaussian minus threshold, clamped
            float g  = exp2f(d * d * -2.8853901f) * 0.79788456f - 0.48394145f;
            float w  = fmaxf(g, 0.f) * FX[dx];
            rn = fmaf(w, nv, rn);
            rd += w;
        }
        num = fmaf(fy, rn, num);
        den = fmaf(fy, rd, den);
    }

    const int pid = ty * TS + tx;
    red_n[tz][pid] = num;
    red_d[tz][pid] = den;
    __syncthreads();

    if (tz == 0) {
        float n = red_n[0][pid] + red_n[1][pid];
        float d = red_d[0][pid] + red_d[1][pid];
        // overall scale k = 1/(SSIGMA*sqrt(2pi)) applied here; eps matches reference
        float r = (0.0470158f * n) / (0.0470158f * d + 1e-8f);
        out[b * IMG * IMG + (by0 + ty) * IMG + (bx0 + tx)] = r;
    }
}

extern "C" void kernel_launch(void* const* d_in, const int* in_sizes, int n_in,
                              void* d_out, int out_size, void* d_ws, size_t ws_size,
                              hipStream_t stream) {
    const float* in  = (const float*)d_in[0];
    float* out = (float*)d_out;
    float* ws  = (float*)d_ws;   // needs 2*192*192*4 = 294912 bytes

    dim3 grid(IMG / TS, IMG / TS, 2);   // 12 x 12 x 2 = 288 blocks
    dim3 block(TS, TS, 2);              // 512 threads

    ms_iter<<<grid, block, 0, stream>>>(in, out);   // iter 1: features -> out
    ms_iter<<<grid, block, 0, stream>>>(out, ws);   // iter 2: out -> ws
    ms_iter<<<grid, block, 0, stream>>>(ws, out);   // iter 3: ws -> out
}

// Round 2
// 50.229 us; speedup vs baseline: 1.2433x; 1.2433x over previous
//
#include <hip/hip_runtime.h>

#define SR   9
#define SD   19
#define TW   16                 // tile width in pixels
#define TH   4                  // tile height in pixels
#define LW   (TW + 2*SR)        // 34 staged cols
#define LH   (TH + 2*SR)        // 22 staged rows
#define LS   40                 // LDS row stride (floats); 40 % 32 == 8 -> conflict-free b64 reads
#define IMG  192
#define NPIX (IMG*IMG)

// FY[t] = exp(-(t-9)^2 / 144)  (separable spatial gaussian factor)
__constant__ float c_FY[SD] = {
    0.5697829f, 0.6411806f, 0.7115726f, 0.7788008f, 0.8406238f,
    0.8948393f, 0.9394131f, 0.9726045f, 0.9930797f, 1.0000000f,
    0.9930797f, 0.9726045f, 0.9394131f, 0.8948393f, 0.8406238f,
    0.7788008f, 0.7115726f, 0.6411806f, 0.5697829f
};

__global__ __launch_bounds__(256) void ms_iter(const float* __restrict__ in,
                                               float* __restrict__ out) {
    __shared__ __align__(16) float tile[LH * LS];
    __shared__ float4 part[4][32];

    const int b   = blockIdx.z;
    const int bx0 = blockIdx.x * TW;
    const int by0 = blockIdx.y * TH;
    const float* __restrict__ img = in + b * NPIX;

    const int tx  = threadIdx.x;            // 0..7
    const int ty  = threadIdx.y;            // 0..3
    const int tz  = threadIdx.z;            // 0..7  (dy group)
    const int tid = tx + 8*ty + 32*tz;      // 0..255

    // stage padded tile (replication pad via clamp)
    for (int i = tid; i < LH*LW; i += 256) {
        int r  = i / LW, c = i - r*LW;
        int gy = min(max(by0 + r - SR, 0), IMG-1);
        int gx = min(max(bx0 + c - SR, 0), IMG-1);
        tile[r*LS + c] = img[gy*IMG + gx];
    }
    __syncthreads();

    const int   x0 = 2*tx;                                 // pixel pair base
    const float cA = tile[(ty+SR)*LS + x0 + SR];
    const float cB = tile[(ty+SR)*LS + x0 + SR + 1];

    constexpr float FX[SD] = {
        0.5697829f, 0.6411806f, 0.7115726f, 0.7788008f, 0.8406238f,
        0.8948393f, 0.9394131f, 0.9726045f, 0.9930797f, 1.0000000f,
        0.9930797f, 0.9726045f, 0.9394131f, 0.8948393f, 0.8406238f,
        0.7788008f, 0.7115726f, 0.6411806f, 0.5697829f
    };
    const float KEXP = -2.88539008f;   // -2/ln2
    const float THR  = 0.60653066f;    // exp(-1/2) = RNG_THR / gauss-amplitude

    // dy groups, balanced so each wave (2 tz) gets 5 rows (last gets 4):
    // rows per tz: {3,2,3,2,3,2,2,2}, begins {0,3,5,8,10,13,15,17}
    const int beg = (int)((0x110F0D0A08050300ULL >> (8*tz)) & 0xFF);
    const int nr  = (int)((0x22232323u >> (4*tz)) & 0xF);

    float numA=0.f, denA=0.f, numB=0.f, denB=0.f;
    for (int r = 0; r < nr; ++r) {
        const int   dy = beg + r;
        const float fy = c_FY[dy];
        const float2* r2 = reinterpret_cast<const float2*>(&tile[(ty+dy)*LS + x0]);
        float w20[20];
#pragma unroll
        for (int j = 0; j < 10; ++j) { float2 v = r2[j]; w20[2*j] = v.x; w20[2*j+1] = v.y; }

        float rnA=0.f, rdA=0.f, rnB=0.f, rdB=0.f;
#pragma unroll
        for (int dx = 0; dx < SD; ++dx) {
            float nA = w20[dx], nB = w20[dx+1];
            float dA = cA - nA,  dB = cB - nB;
            float eA = exp2f(dA*dA*KEXP);
            float eB = exp2f(dB*dB*KEXP);
            float tA = fmaxf(eA - THR, 0.f);
            float tB = fmaxf(eB - THR, 0.f);
            float wA = (0.7978845608f * FX[dx]) * tA;   // const folds to one literal
            float wB = (0.7978845608f * FX[dx]) * tB;
            rnA = fmaf(wA, nA, rnA); rdA += wA;
            rnB = fmaf(wB, nB, rnB); rdB += wB;
        }
        numA = fmaf(fy, rnA, numA); denA = fmaf(fy, rdA, denA);
        numB = fmaf(fy, rnB, numB); denB = fmaf(fy, rdB, denB);
    }

    // combine the two tz groups sharing a wave
    numA += __shfl_down(numA, 32);
    denA += __shfl_down(denA, 32);
    numB += __shfl_down(numB, 32);
    denB += __shfl_down(denB, 32);

    const int wave = tid >> 6;
    const int lane = tid & 63;
    if (lane < 32) part[wave][lane] = make_float4(numA, denA, numB, denB);
    __syncthreads();

    if (tid < 32) {
        float4 p0 = part[0][tid], p1 = part[1][tid];
        float4 p2 = part[2][tid], p3 = part[3][tid];
        float nA = p0.x + p1.x + p2.x + p3.x;
        float dA = p0.y + p1.y + p2.y + p3.y;
        float nB = p0.z + p1.z + p2.z + p3.z;
        float dB = p0.w + p1.w + p2.w + p3.w;
        const float K = 0.04701581f;   // 1/(SSIGMA*sqrt(2pi))
        float2 o;
        o.x = (K*nA) / (K*dA + 1e-8f);
        o.y = (K*nB) / (K*dB + 1e-8f);
        const int px = tid & 7, py = tid >> 3;
        *reinterpret_cast<float2*>(&out[b*NPIX + (by0+py)*IMG + bx0 + 2*px]) = o;
    }
}

extern "C" void kernel_launch(void* const* d_in, const int* in_sizes, int n_in,
                              void* d_out, int out_size, void* d_ws, size_t ws_size,
                              hipStream_t stream) {
    const float* in  = (const float*)d_in[0];
    float* out = (float*)d_out;
    float* ws  = (float*)d_ws;   // needs 2*192*192*4 = 294912 bytes

    dim3 grid(IMG / TW, IMG / TH, 2);   // 12 x 48 x 2 = 1152 blocks
    dim3 block(8, 4, 8);                // 256 threads = 4 waves

    ms_iter<<<grid, block, 0, stream>>>(in, out);   // iter 1
    ms_iter<<<grid, block, 0, stream>>>(out, ws);   // iter 2
    ms_iter<<<grid, block, 0, stream>>>(ws, out);   // iter 3
}

// Round 3
// 35.484 us; speedup vs baseline: 1.7599x; 1.4155x over previous
//
#include <hip/hip_runtime.h>

#define SR   9
#define SD   19
#define TW   16                 // tile width in pixels
#define TH   4                  // tile height in pixels
#define LW   (TW + 2*SR)        // 34 staged cols
#define LH   (TH + 2*SR)        // 22 staged rows
#define LS   40                 // LDS row stride (floats); 40 % 32 == 8 -> conflict-free b64 reads
#define IMG  192
#define NPIX (IMG*IMG)

__global__ __launch_bounds__(256) void ms_iter(const float* __restrict__ in,
                                               float* __restrict__ out) {
    __shared__ __align__(16) float tile[LH * LS];
    __shared__ float4 part[4][32];

    const int b   = blockIdx.z;
    const int bx0 = blockIdx.x * TW;
    const int by0 = blockIdx.y * TH;
    const float* __restrict__ img = in + b * NPIX;

    const int tx  = threadIdx.x;            // 0..7
    const int ty  = threadIdx.y;            // 0..3
    const int tz  = threadIdx.z;            // 0..7  (dy group)
    const int tid = tx + 8*ty + 32*tz;      // 0..255

    // stage padded tile (replication pad via clamp)
    for (int i = tid; i < LH*LW; i += 256) {
        int r  = i / LW, c = i - r*LW;
        int gy = min(max(by0 + r - SR, 0), IMG-1);
        int gx = min(max(bx0 + c - SR, 0), IMG-1);
        tile[r*LS + c] = img[gy*IMG + gx];
    }
    __syncthreads();

    // FX[dx] premultiplied by the range-gaussian amplitude 1/(0.5*sqrt(2pi)):
    // C[dx] = 0.7978845608 * exp(-(dx-9)^2/144)
    constexpr float CX[SD] = {
        0.45461166f, 0.51157701f, 0.56774066f, 0.62138379f, 0.67071069f,
        0.71397332f, 0.74953931f, 0.77602279f, 0.79236573f, 0.79788456f,
        0.79236573f, 0.77602279f, 0.74953931f, 0.71397332f, 0.67071069f,
        0.62138379f, 0.56774066f, 0.51157701f, 0.45461166f
    };
    const float RSIG = 1.69864365f;    // sqrt(2*log2(e))  -> exp(-2d^2) = exp2(-(d*RSIG)^2)
    const float THR  = 0.60653066f;    // exp(-1/2): range weight zero-crossing

    const int   x0 = 2*tx;                                 // pixel pair base
    const float crA = tile[(ty+SR)*LS + x0 + SR]     * RSIG;
    const float crB = tile[(ty+SR)*LS + x0 + SR + 1] * RSIG;

    // per-tz row ranges; tz pairs within a wave have equal counts (no intra-wave
    // divergence except wave 3: {2,1}):  nr = {3,3,2,2,3,3,2,1}
    const int beg = (int)((0x12100D0A08060300ULL >> (8*tz)) & 0xFF);
    const int nr  = (int)((0x12332233u >> (4*tz)) & 0xF);

    float numA=0.f, denA=0.f, numB=0.f, denB=0.f;
    for (int r = 0; r < nr; ++r) {
        const int dy = beg + r;
        // fy = exp(-(dy-9)^2/144) computed in-register (dy is lane-varying,
        // so a table load would be a per-lane global load)
        const float ft = (float)(dy - 9);
        const float fy = __builtin_amdgcn_exp2f(ft * ft * -0.010018715f);

        const float2* r2 = reinterpret_cast<const float2*>(&tile[(ty+dy)*LS + x0]);
        float w20[20];
#pragma unroll
        for (int j = 0; j < 10; ++j) { float2 v = r2[j]; w20[2*j] = v.x; w20[2*j+1] = v.y; }

        float rnA=0.f, rdA=0.f, rnB=0.f, rdB=0.f;
#pragma unroll
        for (int dx = 0; dx < SD; ++dx) {
            float nA = w20[dx], nB = w20[dx+1];
            float sA = fmaf(nA, -RSIG, crA);
            float sB = fmaf(nB, -RSIG, crB);
            float eA = __builtin_amdgcn_exp2f(-sA*sA);
            float eB = __builtin_amdgcn_exp2f(-sB*sB);
            float tA = fmaxf(eA - THR, 0.f);
            float tB = fmaxf(eB - THR, 0.f);
            float wA = CX[dx] * tA;
            float wB = CX[dx] * tB;
            rnA = fmaf(wA, nA, rnA); rdA += wA;
            rnB = fmaf(wB, nB, rnB); rdB += wB;
        }
        numA = fmaf(fy, rnA, numA); denA = fmaf(fy, rdA, denA);
        numB = fmaf(fy, rnB, numB); denB = fmaf(fy, rdB, denB);
    }

    // combine the two tz groups sharing a wave
    numA += __shfl_down(numA, 32);
    denA += __shfl_down(denA, 32);
    numB += __shfl_down(numB, 32);
    denB += __shfl_down(denB, 32);

    const int wave = tid >> 6;
    const int lane = tid & 63;
    if (lane < 32) part[wave][lane] = make_float4(numA, denA, numB, denB);
    __syncthreads();

    if (tid < 32) {
        float4 p0 = part[0][tid], p1 = part[1][tid];
        float4 p2 = part[2][tid], p3 = part[3][tid];
        float nA = p0.x + p1.x + p2.x + p3.x;
        float dA = p0.y + p1.y + p2.y + p3.y;
        float nB = p0.z + p1.z + p2.z + p3.z;
        float dB = p0.w + p1.w + p2.w + p3.w;
        const float K = 0.04701581f;   // 1/(SSIGMA*sqrt(2pi)) (spatial amplitude)
        float2 o;
        o.x = (K*nA) / (K*dA + 1e-8f);
        o.y = (K*nB) / (K*dB + 1e-8f);
        const int px = tid & 7, py = tid >> 3;
        *reinterpret_cast<float2*>(&out[b*NPIX + (by0+py)*IMG + bx0 + 2*px]) = o;
    }
}

extern "C" void kernel_launch(void* const* d_in, const int* in_sizes, int n_in,
                              void* d_out, int out_size, void* d_ws, size_t ws_size,
                              hipStream_t stream) {
    const float* in  = (const float*)d_in[0];
    float* out = (float*)d_out;
    float* ws  = (float*)d_ws;   // needs 2*192*192*4 = 294912 bytes

    dim3 grid(IMG / TW, IMG / TH, 2);   // 12 x 48 x 2 = 1152 blocks
    dim3 block(8, 4, 8);                // 256 threads = 4 waves

    ms_iter<<<grid, block, 0, stream>>>(in, out);   // iter 1
    ms_iter<<<grid, block, 0, stream>>>(out, ws);   // iter 2
    ms_iter<<<grid, block, 0, stream>>>(ws, out);   // iter 3
}